// Round 4
// baseline (702.975 us; speedup 1.0000x reference)
//
#include <hip/hip_runtime.h>
#include <hip/hip_bf16.h>

typedef unsigned short u16;
typedef __attribute__((ext_vector_type(8))) short bf16x8;
typedef __attribute__((ext_vector_type(4))) float f32x4;
typedef __attribute__((ext_vector_type(4))) unsigned short u16x4;
typedef __attribute__((ext_vector_type(4))) unsigned int u32x4;

__device__ __forceinline__ u16 f2bf(float f) {
    unsigned u = __float_as_uint(f);
    u += 0x7fffu + ((u >> 16) & 1u);
    return (u16)(u >> 16);
}
__device__ __forceinline__ float bf2f(u16 u) {
    return __uint_as_float(((unsigned)u) << 16);
}

// ---------------- weight transpose + convert: Wt[n][k] = bf16(W[k][n]) ----------
__global__ __launch_bounds__(256)
void wt_kernel(const float* __restrict__ Wq, const float* __restrict__ Wk,
               const float* __restrict__ Wv, const float* __restrict__ Wo,
               u16* __restrict__ Wt) {
    const float* W = blockIdx.z == 0 ? Wq : blockIdx.z == 1 ? Wk : blockIdx.z == 2 ? Wv : Wo;
    u16* Out = Wt + (size_t)blockIdx.z * (1024 * 1024);
    __shared__ float T[64][65];
    const int t = threadIdx.x;
    const int r0 = blockIdx.y * 64, c0 = blockIdx.x * 64;
#pragma unroll
    for (int e = 0; e < 4; ++e) {
        int row = e * 16 + (t >> 4), c4 = (t & 15) * 4;
        f32x4 v = *(const f32x4*)(W + (r0 + row) * 1024 + c0 + c4);
        T[row][c4] = v[0]; T[row][c4 + 1] = v[1]; T[row][c4 + 2] = v[2]; T[row][c4 + 3] = v[3];
    }
    __syncthreads();
#pragma unroll
    for (int e = 0; e < 4; ++e) {
        int orow = e * 16 + (t >> 4), oc4 = (t & 15) * 4;
        u16x4 pk = { f2bf(T[oc4][orow]), f2bf(T[oc4 + 1][orow]),
                     f2bf(T[oc4 + 2][orow]), f2bf(T[oc4 + 3][orow]) };
        *(u16x4*)(Out + (c0 + orow) * 1024 + r0 + oc4) = pk;
    }
}

// ---------------- GEMM: C[8192][1024] = A[8192][1024] * W  (Bt = W^T bf16) ------
template <int AF32, int BIAS>
__global__ __launch_bounds__(256)
void gemm_kernel(const void* __restrict__ Av, const u16* __restrict__ Bt,
                 u16* __restrict__ Cb, float* __restrict__ Cf,
                 const float* __restrict__ bias) {
    constexpr int K = 1024;
    __shared__ u16 As[128 * 64];
    __shared__ u16 Bs[128 * 64];
    const int tid = threadIdx.x;
    const int lane = tid & 63, w = tid >> 6;
    const int wr = w >> 1, wc = w & 1;
    const int c = lane & 15, g = lane >> 4;
    const int m0 = blockIdx.y * 128, n0 = blockIdx.x * 128;
    const float* Af = (const float*)Av;
    const u16* Ab = (const u16*)Av;
    f32x4 acc[4][4] = {};
    for (int kt = 0; kt < 16; ++kt) {
        const int k0 = kt * 64;
        if (AF32) {
#pragma unroll
            for (int i = 0; i < 8; ++i) {
                int idx = i * 256 + tid;
                int row = idx >> 4, c4 = (idx & 15) * 4;
                f32x4 v = *(const f32x4*)(Af + (m0 + row) * K + k0 + c4);
                u16x4 pk = { f2bf(v[0]), f2bf(v[1]), f2bf(v[2]), f2bf(v[3]) };
                *(u16x4*)&As[row * 64 + c4] = pk;
            }
        } else {
#pragma unroll
            for (int i = 0; i < 4; ++i) {
                int idx = i * 256 + tid;
                int row = idx >> 3, c8 = (idx & 7) * 8;
                u32x4 v = *(const u32x4*)(Ab + (m0 + row) * K + k0 + c8);
                *(u32x4*)&As[row * 64 + c8] = v;
            }
        }
#pragma unroll
        for (int i = 0; i < 4; ++i) {
            int idx = i * 256 + tid;
            int row = idx >> 3, c8 = (idx & 7) * 8;
            u32x4 v = *(const u32x4*)(Bt + (n0 + row) * K + k0 + c8);
            *(u32x4*)&Bs[row * 64 + c8] = v;
        }
        __syncthreads();
#pragma unroll
        for (int kk = 0; kk < 2; ++kk) {
            bf16x8 af[4], bfr[4];
#pragma unroll
            for (int m = 0; m < 4; ++m)
                af[m] = *(const bf16x8*)&As[(wr * 64 + m * 16 + c) * 64 + kk * 32 + 8 * g];
#pragma unroll
            for (int n = 0; n < 4; ++n)
                bfr[n] = *(const bf16x8*)&Bs[(wc * 64 + n * 16 + c) * 64 + kk * 32 + 8 * g];
#pragma unroll
            for (int m = 0; m < 4; ++m)
#pragma unroll
                for (int n = 0; n < 4; ++n)
                    acc[m][n] = __builtin_amdgcn_mfma_f32_16x16x32_bf16(af[m], bfr[n], acc[m][n], 0, 0, 0);
        }
        __syncthreads();
    }
#pragma unroll
    for (int n = 0; n < 4; ++n) {
        int col = n0 + wc * 64 + n * 16 + c;
        float bv = BIAS ? bias[col] : 0.0f;
#pragma unroll
        for (int m = 0; m < 4; ++m) {
            int row0 = m0 + wr * 64 + m * 16 + 4 * g;
#pragma unroll
            for (int r = 0; r < 4; ++r) {
                if (BIAS) Cf[(row0 + r) * 1024 + col] = acc[m][n][r] + bv;
                else      Cb[(row0 + r) * 1024 + col] = f2bf(acc[m][n][r]);
            }
        }
    }
}

// ---------------- LayerNorm over D=1024 (bf16 in), write bf16 [bh][s][hd] -------
__global__ __launch_bounds__(256)
void ln_kernel(const u16* __restrict__ P, const float* __restrict__ gamma,
               const float* __restrict__ beta, float mul, u16* __restrict__ Out) {
    const int row = blockIdx.x;
    const int tid = threadIdx.x;
    const int lane = tid & 63, w = tid >> 6;
    u16x4 xr = *(const u16x4*)(P + row * 1024 + tid * 4);
    float x0 = bf2f(xr[0]), x1 = bf2f(xr[1]), x2 = bf2f(xr[2]), x3 = bf2f(xr[3]);
    float s = x0 + x1 + x2 + x3;
    float sq = x0 * x0 + x1 * x1 + x2 * x2 + x3 * x3;
#pragma unroll
    for (int m = 1; m < 64; m <<= 1) { s += __shfl_xor(s, m); sq += __shfl_xor(sq, m); }
    __shared__ float red[8];
    if (lane == 0) { red[w] = s; red[4 + w] = sq; }
    __syncthreads();
    float st = red[0] + red[1] + red[2] + red[3];
    float sqt = red[4] + red[5] + red[6] + red[7];
    float mu = st * (1.0f / 1024.0f);
    float var = sqt * (1.0f / 1024.0f) - mu * mu;
    float rs = rsqrtf(var + 1e-5f);
    f32x4 gm = *(const f32x4*)(gamma + tid * 4);
    f32x4 bt = *(const f32x4*)(beta + tid * 4);
    float xs[4] = {x0, x1, x2, x3};
    u16x4 pk;
#pragma unroll
    for (int j = 0; j < 4; ++j)
        pk[j] = f2bf(((xs[j] - mu) * rs * gm[j] + bt[j]) * mul);
    const int b = row >> 11, sI = row & 2047;
    const int col = tid * 4, hh = col >> 6, d = col & 63;
    *(u16x4*)(Out + (((b * 16 + hh) * 2048 + sI) << 6) + d) = pk;
}

// ---------------- V transpose: Vt[bh][64][S] (bf16 in/out) ----------------------
__global__ __launch_bounds__(256)
void vt_kernel(const u16* __restrict__ P, u16* __restrict__ Vt) {
    __shared__ u16 T[64][72];
    const int t = threadIdx.x;
    const int bh = blockIdx.y, s0 = blockIdx.x * 64;
    const int b = bh >> 4, h = bh & 15;
#pragma unroll
    for (int e = 0; e < 4; ++e) {
        int row = e * 16 + (t >> 4), c4 = (t & 15) * 4;
        u16x4 v = *(const u16x4*)(P + (b * 2048 + s0 + row) * 1024 + h * 64 + c4);
        *(u16x4*)&T[row][c4] = v;
    }
    __syncthreads();
#pragma unroll
    for (int e = 0; e < 4; ++e) {
        int dd = e * 16 + (t >> 4), s4 = (t & 15) * 4;
        u16x4 pk = { T[s4][dd], T[s4 + 1][dd], T[s4 + 2][dd], T[s4 + 3][dd] };
        *(u16x4*)(Vt + ((size_t)bh * 64 + dd) * 2048 + s0 + s4) = pk;
    }
}

// ---------------- flash attention: swapped QK^T, lane-local softmax -------------
// Each wave owns 16 q-rows; no inter-wave barriers (P-LDS is wave-private).
// S^T = mfma(K_frag, Q_frag): lane (c,g) holds S[q=c][k=16ct+4g+r], so the
// tile max/sum are 31 lane-local ops + 2 shfl_xor (masks 16,32).
__global__ __launch_bounds__(256)
void attn_kernel(const u16* __restrict__ Qa, const u16* __restrict__ Ka,
                 const u16* __restrict__ Vt, u16* __restrict__ Xa) {
    __shared__ u16 Pl[4 * 16 * 136];
    const int tid = threadIdx.x;
    const int lane = tid & 63, w = tid >> 6;
    const int c = lane & 15, g = lane >> 4;
    const int bh = blockIdx.y, q0 = blockIdx.x * 64;
    const int b = bh >> 4, h = bh & 15;
    const int qrow = q0 + w * 16 + c;
    const u16* qptr = Qa + (bh * 2048 + qrow) * 64;
    bf16x8 qf0 = *(const bf16x8*)(qptr + 8 * g);
    bf16x8 qf1 = *(const bf16x8*)(qptr + 32 + 8 * g);
    f32x4 o[4] = {};
    float mx = -1e30f, li = 0.f;
    u16* pbase = &Pl[w * 16 * 136];
    for (int t = 0; t < 16; ++t) {
        const int kb = t * 128;
        f32x4 sacc[8] = {};
        const u16* kp = Ka + (bh * 2048 + kb + c) * 64 + 8 * g;
#pragma unroll
        for (int ct = 0; ct < 8; ++ct) {
            bf16x8 kf0 = *(const bf16x8*)(kp + ct * 1024);
            bf16x8 kf1 = *(const bf16x8*)(kp + ct * 1024 + 32);
            sacc[ct] = __builtin_amdgcn_mfma_f32_16x16x32_bf16(kf0, qf0, sacc[ct], 0, 0, 0);
            sacc[ct] = __builtin_amdgcn_mfma_f32_16x16x32_bf16(kf1, qf1, sacc[ct], 0, 0, 0);
        }
        // lane-local tile max over 32 values, then reduce across the 4 g-groups
        float tm = fmaxf(fmaxf(sacc[0][0], sacc[0][1]), fmaxf(sacc[0][2], sacc[0][3]));
#pragma unroll
        for (int ct = 1; ct < 8; ++ct) {
            float t2 = fmaxf(fmaxf(sacc[ct][0], sacc[ct][1]), fmaxf(sacc[ct][2], sacc[ct][3]));
            tm = fmaxf(tm, t2);
        }
        tm = fmaxf(tm, __shfl_xor(tm, 16));
        tm = fmaxf(tm, __shfl_xor(tm, 32));
        float nm = fmaxf(mx, tm);
        float fr = exp2f(mx - nm);
        mx = nm;
        float ts = 0.f;
#pragma unroll
        for (int ct = 0; ct < 8; ++ct) {
            float e0 = exp2f(sacc[ct][0] - nm);
            float e1 = exp2f(sacc[ct][1] - nm);
            float e2 = exp2f(sacc[ct][2] - nm);
            float e3 = exp2f(sacc[ct][3] - nm);
            ts += (e0 + e1) + (e2 + e3);
            u16x4 pk = { f2bf(e0), f2bf(e1), f2bf(e2), f2bf(e3) };
            *(u16x4*)&pbase[c * 136 + ct * 16 + 4 * g] = pk;
        }
        ts += __shfl_xor(ts, 16);
        ts += __shfl_xor(ts, 32);
        li = li * fr + ts;
        // broadcast rescale factor from q=c lanes to (g,r) accumulator lanes
        float f0 = __shfl(fr, 4 * g + 0);
        float f1 = __shfl(fr, 4 * g + 1);
        float f2 = __shfl(fr, 4 * g + 2);
        float f3 = __shfl(fr, 4 * g + 3);
#pragma unroll
        for (int n = 0; n < 4; ++n) {
            o[n][0] *= f0; o[n][1] *= f1; o[n][2] *= f2; o[n][3] *= f3;
        }
        asm volatile("s_waitcnt lgkmcnt(0)" ::: "memory");
#pragma unroll
        for (int s4 = 0; s4 < 4; ++s4) {
            bf16x8 af = *(const bf16x8*)&pbase[c * 136 + 32 * s4 + 8 * g];
            const u16* vp = Vt + ((size_t)bh * 64 + c) * 2048 + kb + 32 * s4 + 8 * g;
#pragma unroll
            for (int n = 0; n < 4; ++n) {
                bf16x8 vf = *(const bf16x8*)(vp + n * 16 * 2048);
                o[n] = __builtin_amdgcn_mfma_f32_16x16x32_bf16(af, vf, o[n], 0, 0, 0);
            }
        }
    }
    float inv = 1.0f / li;
    float i0 = __shfl(inv, 4 * g + 0);
    float i1 = __shfl(inv, 4 * g + 1);
    float i2 = __shfl(inv, 4 * g + 2);
    float i3 = __shfl(inv, 4 * g + 3);
    float iv[4] = {i0, i1, i2, i3};
#pragma unroll
    for (int r = 0; r < 4; ++r) {
        int row = q0 + w * 16 + 4 * g + r;
        u16* xp = Xa + (b * 2048 + row) * 1024 + h * 64;
#pragma unroll
        for (int n = 0; n < 4; ++n)
            xp[n * 16 + c] = f2bf(o[n][r] * iv[r]);
    }
}

// ---------------- launch --------------------------------------------------------
extern "C" void kernel_launch(void* const* d_in, const int* in_sizes, int n_in,
                              void* d_out, int out_size, void* d_ws, size_t ws_size,
                              hipStream_t stream) {
    const float* q   = (const float*)d_in[0];
    const float* k   = (const float*)d_in[1];
    const float* v   = (const float*)d_in[2];
    const float* Wq  = (const float*)d_in[3];
    const float* Wk  = (const float*)d_in[4];
    const float* Wv  = (const float*)d_in[5];
    const float* Wo  = (const float*)d_in[6];
    const float* bo  = (const float*)d_in[7];
    const float* qg  = (const float*)d_in[8];
    const float* qbt = (const float*)d_in[9];
    const float* kg  = (const float*)d_in[10];
    const float* kbt = (const float*)d_in[11];

    char* ws = (char*)d_ws;
    u16* Wt = (u16*)(ws);                    //  8,388,608 B
    u16* Pb = (u16*)(ws + 8388608);          // 16,777,216 B
    u16* Qa = (u16*)(ws + 25165824);         // 16,777,216 B
    u16* Ka = (u16*)(ws + 41943040);         // 16,777,216 B
    u16* Vt = (u16*)(ws + 58720256);         // 16,777,216 B (end 75,497,472 = 72 MiB)
    u16* Xa = Pb;                            // reuse: P dead after vt_kernel

    const float MUL_Q = 0.04508422002778f;   // (1/32) * log2(e)

    wt_kernel<<<dim3(16, 16, 4), 256, 0, stream>>>(Wq, Wk, Wv, Wo, Wt);

    gemm_kernel<1, 0><<<dim3(8, 64), 256, 0, stream>>>((const void*)q, Wt, Pb, nullptr, nullptr);
    ln_kernel<<<8192, 256, 0, stream>>>(Pb, qg, qbt, MUL_Q, Qa);

    gemm_kernel<1, 0><<<dim3(8, 64), 256, 0, stream>>>((const void*)k, Wt + 1048576, Pb, nullptr, nullptr);
    ln_kernel<<<8192, 256, 0, stream>>>(Pb, kg, kbt, 1.0f, Ka);

    gemm_kernel<1, 0><<<dim3(8, 64), 256, 0, stream>>>((const void*)v, Wt + 2097152, Pb, nullptr, nullptr);
    vt_kernel<<<dim3(32, 64), 256, 0, stream>>>(Pb, Vt);

    attn_kernel<<<dim3(32, 64), 256, 0, stream>>>(Qa, Ka, Vt, Xa);

    gemm_kernel<0, 1><<<dim3(8, 64), 256, 0, stream>>>((const void*)Xa, Wt + 3145728, nullptr, (float*)d_out, bo);
}

// Round 5
// 366.335 us; speedup vs baseline: 1.9189x; 1.9189x over previous
//
#include <hip/hip_runtime.h>
#include <hip/hip_bf16.h>

typedef unsigned short u16;
typedef __attribute__((ext_vector_type(8))) short bf16x8;
typedef __attribute__((ext_vector_type(4))) float f32x4;
typedef __attribute__((ext_vector_type(4))) unsigned short u16x4;
typedef __attribute__((ext_vector_type(4))) unsigned int u32x4;

__device__ __forceinline__ u16 f2bf(float f) {
    unsigned u = __float_as_uint(f);
    u += 0x7fffu + ((u >> 16) & 1u);
    return (u16)(u >> 16);
}
__device__ __forceinline__ float bf2f(u16 u) {
    return __uint_as_float(((unsigned)u) << 16);
}

// ---------------- weight transpose + convert: Wt[n][k] = bf16(W[k][n]) ----------
__global__ __launch_bounds__(256)
void wt_kernel(const float* __restrict__ Wq, const float* __restrict__ Wk,
               const float* __restrict__ Wv, const float* __restrict__ Wo,
               u16* __restrict__ Wt) {
    const float* W = blockIdx.z == 0 ? Wq : blockIdx.z == 1 ? Wk : blockIdx.z == 2 ? Wv : Wo;
    u16* Out = Wt + (size_t)blockIdx.z * (1024 * 1024);
    __shared__ float T[64][65];
    const int t = threadIdx.x;
    const int r0 = blockIdx.y * 64, c0 = blockIdx.x * 64;
#pragma unroll
    for (int e = 0; e < 4; ++e) {
        int row = e * 16 + (t >> 4), c4 = (t & 15) * 4;
        f32x4 v = *(const f32x4*)(W + (r0 + row) * 1024 + c0 + c4);
        T[row][c4] = v[0]; T[row][c4 + 1] = v[1]; T[row][c4 + 2] = v[2]; T[row][c4 + 3] = v[3];
    }
    __syncthreads();
#pragma unroll
    for (int e = 0; e < 4; ++e) {
        int orow = e * 16 + (t >> 4), oc4 = (t & 15) * 4;
        u16x4 pk = { f2bf(T[oc4][orow]), f2bf(T[oc4 + 1][orow]),
                     f2bf(T[oc4 + 2][orow]), f2bf(T[oc4 + 3][orow]) };
        *(u16x4*)(Out + (c0 + orow) * 1024 + r0 + oc4) = pk;
    }
}

// ---------------- GEMM: C[8192][1024] = A[8192][1024] * W  (Bt = W^T bf16) ------
template <int AF32, int BIAS>
__global__ __launch_bounds__(256)
void gemm_kernel(const void* __restrict__ Av, const u16* __restrict__ Bt,
                 u16* __restrict__ Cb, float* __restrict__ Cf,
                 const float* __restrict__ bias) {
    constexpr int K = 1024;
    __shared__ u16 As[128 * 64];
    __shared__ u16 Bs[128 * 64];
    const int tid = threadIdx.x;
    const int lane = tid & 63, w = tid >> 6;
    const int wr = w >> 1, wc = w & 1;
    const int c = lane & 15, g = lane >> 4;
    const int m0 = blockIdx.y * 128, n0 = blockIdx.x * 128;
    const float* Af = (const float*)Av;
    const u16* Ab = (const u16*)Av;
    f32x4 acc[4][4] = {};
    for (int kt = 0; kt < 16; ++kt) {
        const int k0 = kt * 64;
        if (AF32) {
#pragma unroll
            for (int i = 0; i < 8; ++i) {
                int idx = i * 256 + tid;
                int row = idx >> 4, c4 = (idx & 15) * 4;
                f32x4 v = *(const f32x4*)(Af + (m0 + row) * K + k0 + c4);
                u16x4 pk = { f2bf(v[0]), f2bf(v[1]), f2bf(v[2]), f2bf(v[3]) };
                *(u16x4*)&As[row * 64 + c4] = pk;
            }
        } else {
#pragma unroll
            for (int i = 0; i < 4; ++i) {
                int idx = i * 256 + tid;
                int row = idx >> 3, c8 = (idx & 7) * 8;
                u32x4 v = *(const u32x4*)(Ab + (m0 + row) * K + k0 + c8);
                *(u32x4*)&As[row * 64 + c8] = v;
            }
        }
#pragma unroll
        for (int i = 0; i < 4; ++i) {
            int idx = i * 256 + tid;
            int row = idx >> 3, c8 = (idx & 7) * 8;
            u32x4 v = *(const u32x4*)(Bt + (n0 + row) * K + k0 + c8);
            *(u32x4*)&Bs[row * 64 + c8] = v;
        }
        __syncthreads();
#pragma unroll
        for (int kk = 0; kk < 2; ++kk) {
            bf16x8 af[4], bfr[4];
#pragma unroll
            for (int m = 0; m < 4; ++m)
                af[m] = *(const bf16x8*)&As[(wr * 64 + m * 16 + c) * 64 + kk * 32 + 8 * g];
#pragma unroll
            for (int n = 0; n < 4; ++n)
                bfr[n] = *(const bf16x8*)&Bs[(wc * 64 + n * 16 + c) * 64 + kk * 32 + 8 * g];
#pragma unroll
            for (int m = 0; m < 4; ++m)
#pragma unroll
                for (int n = 0; n < 4; ++n)
                    acc[m][n] = __builtin_amdgcn_mfma_f32_16x16x32_bf16(af[m], bfr[n], acc[m][n], 0, 0, 0);
        }
        __syncthreads();
    }
#pragma unroll
    for (int n = 0; n < 4; ++n) {
        int col = n0 + wc * 64 + n * 16 + c;
        float bv = BIAS ? bias[col] : 0.0f;
#pragma unroll
        for (int m = 0; m < 4; ++m) {
            int row0 = m0 + wr * 64 + m * 16 + 4 * g;
#pragma unroll
            for (int r = 0; r < 4; ++r) {
                if (BIAS) Cf[(row0 + r) * 1024 + col] = acc[m][n][r] + bv;
                else      Cb[(row0 + r) * 1024 + col] = f2bf(acc[m][n][r]);
            }
        }
    }
}

// ---------------- LayerNorm over D=1024 (bf16 in), write bf16 [bh][s][hd] -------
__global__ __launch_bounds__(256)
void ln_kernel(const u16* __restrict__ P, const float* __restrict__ gamma,
               const float* __restrict__ beta, float mul, u16* __restrict__ Out) {
    const int row = blockIdx.x;
    const int tid = threadIdx.x;
    const int lane = tid & 63, w = tid >> 6;
    u16x4 xr = *(const u16x4*)(P + row * 1024 + tid * 4);
    float x0 = bf2f(xr[0]), x1 = bf2f(xr[1]), x2 = bf2f(xr[2]), x3 = bf2f(xr[3]);
    float s = x0 + x1 + x2 + x3;
    float sq = x0 * x0 + x1 * x1 + x2 * x2 + x3 * x3;
#pragma unroll
    for (int m = 1; m < 64; m <<= 1) { s += __shfl_xor(s, m); sq += __shfl_xor(sq, m); }
    __shared__ float red[8];
    if (lane == 0) { red[w] = s; red[4 + w] = sq; }
    __syncthreads();
    float st = red[0] + red[1] + red[2] + red[3];
    float sqt = red[4] + red[5] + red[6] + red[7];
    float mu = st * (1.0f / 1024.0f);
    float var = sqt * (1.0f / 1024.0f) - mu * mu;
    float rs = rsqrtf(var + 1e-5f);
    f32x4 gm = *(const f32x4*)(gamma + tid * 4);
    f32x4 bt = *(const f32x4*)(beta + tid * 4);
    float xs[4] = {x0, x1, x2, x3};
    u16x4 pk;
#pragma unroll
    for (int j = 0; j < 4; ++j)
        pk[j] = f2bf(((xs[j] - mu) * rs * gm[j] + bt[j]) * mul);
    const int b = row >> 11, sI = row & 2047;
    const int col = tid * 4, hh = col >> 6, d = col & 63;
    *(u16x4*)(Out + (((b * 16 + hh) * 2048 + sI) << 6) + d) = pk;
}

// ---------------- V transpose: Vt[bh][64][S] (bf16 in/out) ----------------------
__global__ __launch_bounds__(256)
void vt_kernel(const u16* __restrict__ P, u16* __restrict__ Vt) {
    __shared__ u16 T[64][72];
    const int t = threadIdx.x;
    const int bh = blockIdx.y, s0 = blockIdx.x * 64;
    const int b = bh >> 4, h = bh & 15;
#pragma unroll
    for (int e = 0; e < 4; ++e) {
        int row = e * 16 + (t >> 4), c4 = (t & 15) * 4;
        u16x4 v = *(const u16x4*)(P + (b * 2048 + s0 + row) * 1024 + h * 64 + c4);
        *(u16x4*)&T[row][c4] = v;
    }
    __syncthreads();
#pragma unroll
    for (int e = 0; e < 4; ++e) {
        int dd = e * 16 + (t >> 4), s4 = (t & 15) * 4;
        u16x4 pk = { T[s4][dd], T[s4 + 1][dd], T[s4 + 2][dd], T[s4 + 3][dd] };
        *(u16x4*)(Vt + ((size_t)bh * 64 + dd) * 2048 + s0 + s4) = pk;
    }
}

// ---------------- flash attention v3: LDS-staged KV, 2-phase pipeline -----------
// 4 waves/block share double-buffered K-tile [128k][64d] + V-tile [64d][128s] in
// LDS (XOR-swizzled, byte ^= (row&7)<<4). Swapped QK^T (lane-local softmax).
// Per tile: issue next-tile global loads -> QK -> softmax -> PV -> ds_write next
// -> one barrier. XCD-aware block swizzle for K/V L2 locality.
__global__ __launch_bounds__(256)
void attn_kernel(const u16* __restrict__ Qa, const u16* __restrict__ Ka,
                 const u16* __restrict__ Vt, const u16* __restrict__ Xa_unused,
                 u16* __restrict__ Xa) {
    __shared__ u16 Ks[2][8192];   // 16KB each: [128][64] swizzled
    __shared__ u16 Vs[2][8192];   // 16KB each: [64][128] swizzled
    __shared__ u16 Pl[4][2048];   // 4KB/wave: [16 q][128 k] swizzled
    const int tid = threadIdx.x;
    const int lane = tid & 63, w = tid >> 6;
    const int c = lane & 15, g = lane >> 4;
    // XCD swizzle: 8 bh-groups per XCD -> per-XCD KV working set ~4MB (fits L2)
    const int bid = blockIdx.x;
    const int bh = (bid & 7) * 8 + ((bid >> 3) & 7);
    const int q0 = (bid >> 6) * 64;
    const int b = bh >> 4, h = bh & 15;

    const int qrow = q0 + w * 16 + c;
    const u16* qptr = Qa + ((size_t)bh * 2048 + qrow) * 64;
    bf16x8 qf0 = *(const bf16x8*)(qptr + 8 * g);
    bf16x8 qf1 = *(const bf16x8*)(qptr + 32 + 8 * g);

    // staging geometry (per wave: 4 K-loads + 4 V-loads of b128 per tile)
    const int krow = w * 32 + (lane >> 3);              // +8 per j
    const u16* kS = Ka + ((size_t)bh * 2048 + krow) * 64 + (lane & 7) * 8;
    const int kds = krow * 128 + (((lane & 7) * 16) ^ ((lane >> 3) << 4)); // +1024 per j
    const int vd0 = w * 16 + (lane >> 4);               // +4 per j
    const u16* vS = Vt + ((size_t)bh * 64 + vd0) * 2048 + (lane & 15) * 8;
    const int vcol = (lane & 15) * 16;
    const int vxe = ((lane >> 4) & 7) << 4;             // swizzle for j even
    const int vxo = (((lane >> 4) + 4) & 7) << 4;       // swizzle for j odd
    const int pswz = (c & 7) << 4;

    f32x4 o[4] = {};
    float mx = -1e30f, li = 0.f;
    char* pb = (char*)&Pl[w][0];

    // ---- prologue: stage tile 0 into buffer 0
    {
        u32x4 kreg[4], vreg[4];
#pragma unroll
        for (int j = 0; j < 4; ++j) kreg[j] = *(const u32x4*)(kS + j * 512);
#pragma unroll
        for (int j = 0; j < 4; ++j) vreg[j] = *(const u32x4*)(vS + j * 8192);
        char* kd = (char*)&Ks[0][0];
        char* vd = (char*)&Vs[0][0];
#pragma unroll
        for (int j = 0; j < 4; ++j) *(u32x4*)(kd + kds + j * 1024) = kreg[j];
#pragma unroll
        for (int j = 0; j < 4; ++j)
            *(u32x4*)(vd + vd0 * 256 + j * 1024 + (vcol ^ ((j & 1) ? vxo : vxe))) = vreg[j];
    }
    __syncthreads();

    int cur = 0;
    for (int t = 0; t < 16; ++t) {
        // ---- issue next-tile loads (land under this tile's compute)
        const int tn = (t + 1) & 15;
        u32x4 kreg[4], vreg[4];
#pragma unroll
        for (int j = 0; j < 4; ++j) kreg[j] = *(const u32x4*)(kS + tn * 8192 + j * 512);
#pragma unroll
        for (int j = 0; j < 4; ++j) vreg[j] = *(const u32x4*)(vS + tn * 128 + j * 8192);

        // ---- QK^T from Ks[cur] (swapped: lane (c,g) -> S[k=16ct+4g+r][q=c])
        const char* kbase = (const char*)&Ks[cur][0];
        f32x4 sacc[8] = {};
#pragma unroll
        for (int ct = 0; ct < 8; ++ct) {
            const int rb = (c + 16 * ct) * 128;
            bf16x8 kf0 = *(const bf16x8*)(kbase + rb + ((16 * g) ^ pswz));
            bf16x8 kf1 = *(const bf16x8*)(kbase + rb + ((64 + 16 * g) ^ pswz));
            sacc[ct] = __builtin_amdgcn_mfma_f32_16x16x32_bf16(kf0, qf0, sacc[ct], 0, 0, 0);
            sacc[ct] = __builtin_amdgcn_mfma_f32_16x16x32_bf16(kf1, qf1, sacc[ct], 0, 0, 0);
        }

        // ---- online softmax (lane-local over 32 k, reduce across 4 g-groups)
        float tm = fmaxf(fmaxf(sacc[0][0], sacc[0][1]), fmaxf(sacc[0][2], sacc[0][3]));
#pragma unroll
        for (int ct = 1; ct < 8; ++ct) {
            float t2 = fmaxf(fmaxf(sacc[ct][0], sacc[ct][1]), fmaxf(sacc[ct][2], sacc[ct][3]));
            tm = fmaxf(tm, t2);
        }
        tm = fmaxf(tm, __shfl_xor(tm, 16));
        tm = fmaxf(tm, __shfl_xor(tm, 32));
        float nm = fmaxf(mx, tm);
        float fr = exp2f(mx - nm);
        mx = nm;
        float ts = 0.f;
#pragma unroll
        for (int ct = 0; ct < 8; ++ct) {
            float e0 = exp2f(sacc[ct][0] - nm);
            float e1 = exp2f(sacc[ct][1] - nm);
            float e2 = exp2f(sacc[ct][2] - nm);
            float e3 = exp2f(sacc[ct][3] - nm);
            ts += (e0 + e1) + (e2 + e3);
            u16x4 pk = { f2bf(e0), f2bf(e1), f2bf(e2), f2bf(e3) };
            *(u16x4*)(pb + 256 * c + ((32 * ct + 8 * g) ^ pswz)) = pk;
        }
        ts += __shfl_xor(ts, 16);
        ts += __shfl_xor(ts, 32);
        li = li * fr + ts;
        float f0 = __shfl(fr, 4 * g + 0);
        float f1 = __shfl(fr, 4 * g + 1);
        float f2 = __shfl(fr, 4 * g + 2);
        float f3 = __shfl(fr, 4 * g + 3);
#pragma unroll
        for (int n = 0; n < 4; ++n) {
            o[n][0] *= f0; o[n][1] *= f1; o[n][2] *= f2; o[n][3] *= f3;
        }

        // ---- PV from Pl (own wave) and Vs[cur]
        const char* vb = (const char*)&Vs[cur][0];
#pragma unroll
        for (int s4 = 0; s4 < 4; ++s4) {
            const int co = ((64 * s4 + 16 * g) ^ pswz);
            bf16x8 af = *(const bf16x8*)(pb + 256 * c + co);
#pragma unroll
            for (int n = 0; n < 4; ++n) {
                bf16x8 vf = *(const bf16x8*)(vb + (c + 16 * n) * 256 + co);
                o[n] = __builtin_amdgcn_mfma_f32_16x16x32_bf16(af, vf, o[n], 0, 0, 0);
            }
        }

        // ---- write staged regs into the other buffer, then barrier
        char* kd = (char*)&Ks[cur ^ 1][0];
        char* vd = (char*)&Vs[cur ^ 1][0];
#pragma unroll
        for (int j = 0; j < 4; ++j) *(u32x4*)(kd + kds + j * 1024) = kreg[j];
#pragma unroll
        for (int j = 0; j < 4; ++j)
            *(u32x4*)(vd + vd0 * 256 + j * 1024 + (vcol ^ ((j & 1) ? vxo : vxe))) = vreg[j];
        __syncthreads();
        cur ^= 1;
    }

    float inv = 1.0f / li;
    float i0 = __shfl(inv, 4 * g + 0);
    float i1 = __shfl(inv, 4 * g + 1);
    float i2 = __shfl(inv, 4 * g + 2);
    float i3 = __shfl(inv, 4 * g + 3);
    float iv[4] = {i0, i1, i2, i3};
#pragma unroll
    for (int r = 0; r < 4; ++r) {
        int row = q0 + w * 16 + 4 * g + r;
        u16* xp = Xa + ((size_t)b * 2048 + row) * 1024 + h * 64;
#pragma unroll
        for (int n = 0; n < 4; ++n)
            xp[n * 16 + c] = f2bf(o[n][r] * iv[r]);
    }
}

// ---------------- launch --------------------------------------------------------
extern "C" void kernel_launch(void* const* d_in, const int* in_sizes, int n_in,
                              void* d_out, int out_size, void* d_ws, size_t ws_size,
                              hipStream_t stream) {
    const float* q   = (const float*)d_in[0];
    const float* k   = (const float*)d_in[1];
    const float* v   = (const float*)d_in[2];
    const float* Wq  = (const float*)d_in[3];
    const float* Wk  = (const float*)d_in[4];
    const float* Wv  = (const float*)d_in[5];
    const float* Wo  = (const float*)d_in[6];
    const float* bo  = (const float*)d_in[7];
    const float* qg  = (const float*)d_in[8];
    const float* qbt = (const float*)d_in[9];
    const float* kg  = (const float*)d_in[10];
    const float* kbt = (const float*)d_in[11];

    char* ws = (char*)d_ws;
    u16* Wt = (u16*)(ws);                    //  8,388,608 B
    u16* Pb = (u16*)(ws + 8388608);          // 16,777,216 B
    u16* Qa = (u16*)(ws + 25165824);         // 16,777,216 B
    u16* Ka = (u16*)(ws + 41943040);         // 16,777,216 B
    u16* Vt = (u16*)(ws + 58720256);         // 16,777,216 B (end 75,497,472 = 72 MiB)
    u16* Xa = Pb;                            // reuse: P dead after vt_kernel

    const float MUL_Q = 0.04508422002778f;   // (1/32) * log2(e)

    wt_kernel<<<dim3(16, 16, 4), 256, 0, stream>>>(Wq, Wk, Wv, Wo, Wt);

    gemm_kernel<1, 0><<<dim3(8, 64), 256, 0, stream>>>((const void*)q, Wt, Pb, nullptr, nullptr);
    ln_kernel<<<8192, 256, 0, stream>>>(Pb, qg, qbt, MUL_Q, Qa);

    gemm_kernel<1, 0><<<dim3(8, 64), 256, 0, stream>>>((const void*)k, Wt + 1048576, Pb, nullptr, nullptr);
    ln_kernel<<<8192, 256, 0, stream>>>(Pb, kg, kbt, 1.0f, Ka);

    gemm_kernel<1, 0><<<dim3(8, 64), 256, 0, stream>>>((const void*)v, Wt + 2097152, Pb, nullptr, nullptr);
    vt_kernel<<<dim3(32, 64), 256, 0, stream>>>(Pb, Vt);

    attn_kernel<<<2048, 256, 0, stream>>>(Qa, Ka, Vt, nullptr, Xa);

    gemm_kernel<0, 1><<<dim3(8, 64), 256, 0, stream>>>((const void*)Xa, Wt + 3145728, nullptr, (float*)d_out, bo);
}

// Round 6
// 334.057 us; speedup vs baseline: 2.1044x; 1.0966x over previous
//
#include <hip/hip_runtime.h>
#include <hip/hip_bf16.h>

typedef unsigned short u16;
typedef __attribute__((ext_vector_type(8))) short bf16x8;
typedef __attribute__((ext_vector_type(4))) float f32x4;
typedef __attribute__((ext_vector_type(4))) unsigned short u16x4;
typedef __attribute__((ext_vector_type(4))) unsigned int u32x4;

__device__ __forceinline__ u16 f2b(float f) {
    __hip_bfloat16 h = __float2bfloat16(f);
    u16 r; __builtin_memcpy(&r, &h, 2); return r;
}
__device__ __forceinline__ float bf2f(u16 u) {
    return __uint_as_float(((unsigned)u) << 16);
}
// async global->LDS, 16B per lane; dest = wave-uniform base + lane*16 (HW)
__device__ __forceinline__ void gload16(const void* g, void* l) {
    __builtin_amdgcn_global_load_lds(
        (const __attribute__((address_space(1))) unsigned int*)g,
        (__attribute__((address_space(3))) unsigned int*)l, 16, 0, 0);
}

// ---------------- weight transpose + convert: Wt[n][k] = bf16(W[k][n]) ----------
__global__ __launch_bounds__(256)
void wt_kernel(const float* __restrict__ Wq, const float* __restrict__ Wk,
               const float* __restrict__ Wv, const float* __restrict__ Wo,
               u16* __restrict__ Wt) {
    const float* W = blockIdx.z == 0 ? Wq : blockIdx.z == 1 ? Wk : blockIdx.z == 2 ? Wv : Wo;
    u16* Out = Wt + (size_t)blockIdx.z * (1024 * 1024);
    __shared__ float T[64][65];
    const int t = threadIdx.x;
    const int r0 = blockIdx.y * 64, c0 = blockIdx.x * 64;
#pragma unroll
    for (int e = 0; e < 4; ++e) {
        int row = e * 16 + (t >> 4), c4 = (t & 15) * 4;
        f32x4 v = *(const f32x4*)(W + (r0 + row) * 1024 + c0 + c4);
        T[row][c4] = v[0]; T[row][c4 + 1] = v[1]; T[row][c4 + 2] = v[2]; T[row][c4 + 3] = v[3];
    }
    __syncthreads();
#pragma unroll
    for (int e = 0; e < 4; ++e) {
        int orow = e * 16 + (t >> 4), oc4 = (t & 15) * 4;
        u16x4 pk = { f2b(T[oc4][orow]), f2b(T[oc4 + 1][orow]),
                     f2b(T[oc4 + 2][orow]), f2b(T[oc4 + 3][orow]) };
        *(u16x4*)(Out + (c0 + orow) * 1024 + r0 + oc4) = pk;
    }
}

// ---------------- GEMM: C[8192][1024] = A[8192][1024] * W  (Bt = W^T bf16) ------
template <int AF32, int BIAS>
__global__ __launch_bounds__(256)
void gemm_kernel(const void* __restrict__ Av, const u16* __restrict__ Bt,
                 u16* __restrict__ Cb, float* __restrict__ Cf,
                 const float* __restrict__ bias) {
    constexpr int K = 1024;
    __shared__ u16 As[128 * 64];
    __shared__ u16 Bs[128 * 64];
    const int tid = threadIdx.x;
    const int lane = tid & 63, w = tid >> 6;
    const int wr = w >> 1, wc = w & 1;
    const int c = lane & 15, g = lane >> 4;
    const int m0 = blockIdx.y * 128, n0 = blockIdx.x * 128;
    const float* Af = (const float*)Av;
    const u16* Ab = (const u16*)Av;
    const int sr = lane >> 3, sc = (lane & 7) * 8;   // staging row/col for gload
    f32x4 acc[4][4] = {};
    for (int kt = 0; kt < 16; ++kt) {
        const int k0 = kt * 64;
        if (AF32) {
#pragma unroll
            for (int i = 0; i < 8; ++i) {
                int idx = i * 256 + tid;
                int row = idx >> 4, c4 = (idx & 15) * 4;
                f32x4 v = *(const f32x4*)(Af + (m0 + row) * K + k0 + c4);
                u16x4 pk = { f2b(v[0]), f2b(v[1]), f2b(v[2]), f2b(v[3]) };
                *(u16x4*)&As[row * 64 + c4] = pk;
            }
        } else {
#pragma unroll
            for (int i = 0; i < 4; ++i) {
                int row = 32 * w + 8 * i;
                gload16(Ab + (size_t)(m0 + row + sr) * K + k0 + sc, &As[row * 64]);
            }
        }
#pragma unroll
        for (int i = 0; i < 4; ++i) {
            int row = 32 * w + 8 * i;
            gload16(Bt + (size_t)(n0 + row + sr) * K + k0 + sc, &Bs[row * 64]);
        }
        __syncthreads();
#pragma unroll
        for (int kk = 0; kk < 2; ++kk) {
            bf16x8 af[4], bfr[4];
#pragma unroll
            for (int m = 0; m < 4; ++m)
                af[m] = *(const bf16x8*)&As[(wr * 64 + m * 16 + c) * 64 + kk * 32 + 8 * g];
#pragma unroll
            for (int n = 0; n < 4; ++n)
                bfr[n] = *(const bf16x8*)&Bs[(wc * 64 + n * 16 + c) * 64 + kk * 32 + 8 * g];
#pragma unroll
            for (int m = 0; m < 4; ++m)
#pragma unroll
                for (int n = 0; n < 4; ++n)
                    acc[m][n] = __builtin_amdgcn_mfma_f32_16x16x32_bf16(af[m], bfr[n], acc[m][n], 0, 0, 0);
        }
        __syncthreads();
    }
#pragma unroll
    for (int n = 0; n < 4; ++n) {
        int col = n0 + wc * 64 + n * 16 + c;
        float bv = BIAS ? bias[col] : 0.0f;
#pragma unroll
        for (int m = 0; m < 4; ++m) {
            int row0 = m0 + wr * 64 + m * 16 + 4 * g;
#pragma unroll
            for (int r = 0; r < 4; ++r) {
                if (BIAS) Cf[(row0 + r) * 1024 + col] = acc[m][n][r] + bv;
                else      Cb[(row0 + r) * 1024 + col] = f2b(acc[m][n][r]);
            }
        }
    }
}

// ---------------- LayerNorm over D=1024 (bf16 in), write bf16 [bh][s][hd] -------
__global__ __launch_bounds__(256)
void ln_kernel(const u16* __restrict__ P, const float* __restrict__ gamma,
               const float* __restrict__ beta, float mul, u16* __restrict__ Out) {
    const int row = blockIdx.x;
    const int tid = threadIdx.x;
    const int lane = tid & 63, w = tid >> 6;
    u16x4 xr = *(const u16x4*)(P + row * 1024 + tid * 4);
    float x0 = bf2f(xr[0]), x1 = bf2f(xr[1]), x2 = bf2f(xr[2]), x3 = bf2f(xr[3]);
    float s = x0 + x1 + x2 + x3;
    float sq = x0 * x0 + x1 * x1 + x2 * x2 + x3 * x3;
#pragma unroll
    for (int m = 1; m < 64; m <<= 1) { s += __shfl_xor(s, m); sq += __shfl_xor(sq, m); }
    __shared__ float red[8];
    if (lane == 0) { red[w] = s; red[4 + w] = sq; }
    __syncthreads();
    float st = red[0] + red[1] + red[2] + red[3];
    float sqt = red[4] + red[5] + red[6] + red[7];
    float mu = st * (1.0f / 1024.0f);
    float var = sqt * (1.0f / 1024.0f) - mu * mu;
    float rs = rsqrtf(var + 1e-5f);
    f32x4 gm = *(const f32x4*)(gamma + tid * 4);
    f32x4 bt = *(const f32x4*)(beta + tid * 4);
    float xs[4] = {x0, x1, x2, x3};
    u16x4 pk;
#pragma unroll
    for (int j = 0; j < 4; ++j)
        pk[j] = f2b(((xs[j] - mu) * rs * gm[j] + bt[j]) * mul);
    const int b = row >> 11, sI = row & 2047;
    const int col = tid * 4, hh = col >> 6, d = col & 63;
    *(u16x4*)(Out + (((b * 16 + hh) * 2048 + sI) << 6) + d) = pk;
}

// ---------------- V transpose: Vt[bh][64][S] (bf16 in/out) ----------------------
__global__ __launch_bounds__(256)
void vt_kernel(const u16* __restrict__ P, u16* __restrict__ Vt) {
    __shared__ u16 T[64][72];
    const int t = threadIdx.x;
    const int bh = blockIdx.y, s0 = blockIdx.x * 64;
    const int b = bh >> 4, h = bh & 15;
#pragma unroll
    for (int e = 0; e < 4; ++e) {
        int row = e * 16 + (t >> 4), c4 = (t & 15) * 4;
        u16x4 v = *(const u16x4*)(P + (b * 2048 + s0 + row) * 1024 + h * 64 + c4);
        *(u16x4*)&T[row][c4] = v;
    }
    __syncthreads();
#pragma unroll
    for (int e = 0; e < 4; ++e) {
        int dd = e * 16 + (t >> 4), s4 = (t & 15) * 4;
        u16x4 pk = { T[s4][dd], T[s4 + 1][dd], T[s4 + 2][dd], T[s4 + 3][dd] };
        *(u16x4*)(Vt + ((size_t)bh * 64 + dd) * 2048 + s0 + s4) = pk;
    }
}

// ---------------- flash attention v4: KVB=64, DMA staging, defer-max ------------
// 4 waves x 16 q-rows; Ks/Vs double-buffered [64][64] bf16, XOR-swizzled via
// pre-swizzled global_load_lds source (linear dest). Swapped QK^T -> lane-local
// softmax; one barrier per tile; defer-max THR=8.
__global__ __launch_bounds__(256)
void attn_kernel(const u16* __restrict__ Qa, const u16* __restrict__ Ka,
                 const u16* __restrict__ Vt, u16* __restrict__ Xa) {
    __shared__ u16 Ks[2][4096];   // 8KB each: [64][64] swizzled
    __shared__ u16 Vs[2][4096];   // 8KB each: [64][64] swizzled (Vt rows = d)
    __shared__ u16 Pl[4][1024];   // 2KB/wave: [16 q][64 k] swizzled
    const int tid = threadIdx.x;
    const int lane = tid & 63, w = tid >> 6;
    const int c = lane & 15, g = lane >> 4;
    const int bid = blockIdx.x;
    const int bh = (bid & 7) * 8 + ((bid >> 3) & 7);
    const int q0 = (bid >> 6) * 64;
    const int b = bh >> 4, h = bh & 15;

    const int qrow = q0 + w * 16 + c;
    const u16* qptr = Qa + ((size_t)bh * 2048 + qrow) * 64;
    bf16x8 qf0 = *(const bf16x8*)(qptr + 8 * g);
    bf16x8 qf1 = *(const bf16x8*)(qptr + 32 + 8 * g);

    // DMA staging: chunk m = 2w+j covers rows [8m,8m+8); source granule pre-swizzled
    const int sr = lane >> 3;
    const int scg = ((lane & 7) ^ sr) * 8;
    const u16* kA = Ka + ((size_t)bh * 2048 + sr) * 64 + scg;
    const u16* vA = Vt + ((size_t)bh * 64 + sr) * 2048 + scg;
    const int pswz = (c & 7) << 4;

    f32x4 o[4] = {};
    float mx = -1e30f, li = 0.f;
    char* pb = (char*)&Pl[w][0];

    // prologue: stage tile 0 into buf 0
#pragma unroll
    for (int j = 0; j < 2; ++j) {
        const int m = 2 * w + j;
        gload16(kA + (size_t)(8 * m) * 64, &Ks[0][8 * m * 64]);
        gload16(vA + (size_t)(8 * m) * 2048, &Vs[0][8 * m * 64]);
    }
    __syncthreads();

    int cur = 0;
    for (int t = 0; t < 32; ++t) {
        // issue async staging of next tile into the other buffer
        const int tn = (t + 1) & 31;
#pragma unroll
        for (int j = 0; j < 2; ++j) {
            const int m = 2 * w + j;
            gload16(kA + (size_t)(tn * 64 + 8 * m) * 64, &Ks[cur ^ 1][8 * m * 64]);
            gload16(vA + (size_t)(8 * m) * 2048 + tn * 64, &Vs[cur ^ 1][8 * m * 64]);
        }

        // QK^T (swapped): sacc[ct][r] = S[k=16ct+4g+r][q=c]
        const char* kbase = (const char*)&Ks[cur][0];
        f32x4 sacc[4] = {};
        __builtin_amdgcn_s_setprio(1);
#pragma unroll
        for (int ct = 0; ct < 4; ++ct) {
            const int rb = (c + 16 * ct) * 128;
            bf16x8 kf0 = *(const bf16x8*)(kbase + rb + ((16 * g) ^ pswz));
            bf16x8 kf1 = *(const bf16x8*)(kbase + rb + ((64 + 16 * g) ^ pswz));
            sacc[ct] = __builtin_amdgcn_mfma_f32_16x16x32_bf16(kf0, qf0, sacc[ct], 0, 0, 0);
            sacc[ct] = __builtin_amdgcn_mfma_f32_16x16x32_bf16(kf1, qf1, sacc[ct], 0, 0, 0);
        }
        __builtin_amdgcn_s_setprio(0);

        // online softmax, defer-max (THR=8)
        float tm = fmaxf(fmaxf(sacc[0][0], sacc[0][1]), fmaxf(sacc[0][2], sacc[0][3]));
#pragma unroll
        for (int ct = 1; ct < 4; ++ct) {
            float t2 = fmaxf(fmaxf(sacc[ct][0], sacc[ct][1]), fmaxf(sacc[ct][2], sacc[ct][3]));
            tm = fmaxf(tm, t2);
        }
        tm = fmaxf(tm, __shfl_xor(tm, 16));
        tm = fmaxf(tm, __shfl_xor(tm, 32));
        const bool skip = __all(tm - mx <= 8.0f) != 0;
        const float nm = skip ? mx : fmaxf(mx, tm);
        float ts = 0.f;
#pragma unroll
        for (int ct = 0; ct < 4; ++ct) {
            float e0 = exp2f(sacc[ct][0] - nm);
            float e1 = exp2f(sacc[ct][1] - nm);
            float e2 = exp2f(sacc[ct][2] - nm);
            float e3 = exp2f(sacc[ct][3] - nm);
            ts += (e0 + e1) + (e2 + e3);
            u16x4 pk = { f2b(e0), f2b(e1), f2b(e2), f2b(e3) };
            *(u16x4*)(pb + 128 * c + ((32 * ct + 8 * g) ^ pswz)) = pk;
        }
        ts += __shfl_xor(ts, 16);
        ts += __shfl_xor(ts, 32);
        if (!skip) {
            float fr = exp2f(mx - nm);
            mx = nm;
            li *= fr;
            float f0 = __shfl(fr, 4 * g + 0);
            float f1 = __shfl(fr, 4 * g + 1);
            float f2 = __shfl(fr, 4 * g + 2);
            float f3 = __shfl(fr, 4 * g + 3);
#pragma unroll
            for (int n = 0; n < 4; ++n) {
                o[n][0] *= f0; o[n][1] *= f1; o[n][2] *= f2; o[n][3] *= f3;
            }
        }
        li += ts;

        // PV from Pl (wave-private) and Vs[cur]
        const char* vb = (const char*)&Vs[cur][0];
        __builtin_amdgcn_s_setprio(1);
#pragma unroll
        for (int s4 = 0; s4 < 2; ++s4) {
            const int co = ((64 * s4 + 16 * g) ^ pswz);
            bf16x8 af = *(const bf16x8*)(pb + 128 * c + co);
#pragma unroll
            for (int n = 0; n < 4; ++n) {
                bf16x8 vf = *(const bf16x8*)(vb + (c + 16 * n) * 128 + co);
                o[n] = __builtin_amdgcn_mfma_f32_16x16x32_bf16(af, vf, o[n], 0, 0, 0);
            }
        }
        __builtin_amdgcn_s_setprio(0);

        __syncthreads();   // next tile staged (vmcnt drained) + all reads of cur done
        cur ^= 1;
    }

    float inv = 1.0f / li;
    float i0 = __shfl(inv, 4 * g + 0);
    float i1 = __shfl(inv, 4 * g + 1);
    float i2 = __shfl(inv, 4 * g + 2);
    float i3 = __shfl(inv, 4 * g + 3);
    float iv[4] = {i0, i1, i2, i3};
#pragma unroll
    for (int r = 0; r < 4; ++r) {
        int row = q0 + w * 16 + 4 * g + r;
        u16* xp = Xa + ((size_t)b * 2048 + row) * 1024 + h * 64;
#pragma unroll
        for (int n = 0; n < 4; ++n)
            xp[n * 16 + c] = f2b(o[n][r] * iv[r]);
    }
}

// ---------------- launch --------------------------------------------------------
extern "C" void kernel_launch(void* const* d_in, const int* in_sizes, int n_in,
                              void* d_out, int out_size, void* d_ws, size_t ws_size,
                              hipStream_t stream) {
    const float* q   = (const float*)d_in[0];
    const float* k   = (const float*)d_in[1];
    const float* v   = (const float*)d_in[2];
    const float* Wq  = (const float*)d_in[3];
    const float* Wk  = (const float*)d_in[4];
    const float* Wv  = (const float*)d_in[5];
    const float* Wo  = (const float*)d_in[6];
    const float* bo  = (const float*)d_in[7];
    const float* qg  = (const float*)d_in[8];
    const float* qbt = (const float*)d_in[9];
    const float* kg  = (const float*)d_in[10];
    const float* kbt = (const float*)d_in[11];

    char* ws = (char*)d_ws;
    u16* Wt = (u16*)(ws);                    //  8,388,608 B
    u16* Pb = (u16*)(ws + 8388608);          // 16,777,216 B
    u16* Qa = (u16*)(ws + 25165824);         // 16,777,216 B
    u16* Ka = (u16*)(ws + 41943040);         // 16,777,216 B
    u16* Vt = (u16*)(ws + 58720256);         // 16,777,216 B (end 75,497,472 = 72 MiB)
    u16* Xa = Pb;                            // reuse: P dead after vt_kernel

    const float MUL_Q = 0.04508422002778f;   // (1/32) * log2(e)

    wt_kernel<<<dim3(16, 16, 4), 256, 0, stream>>>(Wq, Wk, Wv, Wo, Wt);

    gemm_kernel<1, 0><<<dim3(8, 64), 256, 0, stream>>>((const void*)q, Wt, Pb, nullptr, nullptr);
    ln_kernel<<<8192, 256, 0, stream>>>(Pb, qg, qbt, MUL_Q, Qa);

    gemm_kernel<1, 0><<<dim3(8, 64), 256, 0, stream>>>((const void*)k, Wt + 1048576, Pb, nullptr, nullptr);
    ln_kernel<<<8192, 256, 0, stream>>>(Pb, kg, kbt, 1.0f, Ka);

    gemm_kernel<1, 0><<<dim3(8, 64), 256, 0, stream>>>((const void*)v, Wt + 2097152, Pb, nullptr, nullptr);
    vt_kernel<<<dim3(32, 64), 256, 0, stream>>>(Pb, Vt);

    attn_kernel<<<2048, 256, 0, stream>>>(Qa, Ka, Vt, Xa);

    gemm_kernel<0, 1><<<dim3(8, 64), 256, 0, stream>>>((const void*)Xa, Wt + 3145728, nullptr, (float*)d_out, bo);
}

// Round 7
// 294.331 us; speedup vs baseline: 2.3884x; 1.1350x over previous
//
#include <hip/hip_runtime.h>
#include <hip/hip_bf16.h>

typedef unsigned short u16;
typedef __attribute__((ext_vector_type(8))) short bf16x8;
typedef __attribute__((ext_vector_type(4))) float f32x4;
typedef __attribute__((ext_vector_type(4))) unsigned short u16x4;
typedef __attribute__((ext_vector_type(4))) unsigned int u32x4;

__device__ __forceinline__ u16 f2b(float f) {
    __hip_bfloat16 h = __float2bfloat16(f);
    u16 r; __builtin_memcpy(&r, &h, 2); return r;
}
__device__ __forceinline__ float bf2f(u16 u) {
    return __uint_as_float(((unsigned)u) << 16);
}
// async global->LDS, 16B per lane; dest = wave-uniform base + lane*16 (HW)
__device__ __forceinline__ void gload16(const void* g, void* l) {
    __builtin_amdgcn_global_load_lds(
        (const __attribute__((address_space(1))) unsigned int*)g,
        (__attribute__((address_space(3))) unsigned int*)l, 16, 0, 0);
}

// ---------------- fp32 -> bf16 bulk convert (8 elems/thread) --------------------
__global__ __launch_bounds__(256)
void cvt_kernel(const float* __restrict__ in, u16* __restrict__ out) {
    size_t i = ((size_t)blockIdx.x * 256 + threadIdx.x) * 8;
    f32x4 a = *(const f32x4*)(in + i);
    f32x4 b = *(const f32x4*)(in + i + 4);
    u16x4 p0 = { f2b(a[0]), f2b(a[1]), f2b(a[2]), f2b(a[3]) };
    u16x4 p1 = { f2b(b[0]), f2b(b[1]), f2b(b[2]), f2b(b[3]) };
    *(u16x4*)(out + i) = p0;
    *(u16x4*)(out + i + 4) = p1;
}

// ---------------- weight transpose + convert: Wt[n][k] = bf16(W[k][n]) ----------
__global__ __launch_bounds__(256)
void wt_kernel(const float* __restrict__ Wq, const float* __restrict__ Wk,
               const float* __restrict__ Wv, const float* __restrict__ Wo,
               u16* __restrict__ Wt) {
    const float* W = blockIdx.z == 0 ? Wq : blockIdx.z == 1 ? Wk : blockIdx.z == 2 ? Wv : Wo;
    u16* Out = Wt + (size_t)blockIdx.z * (1024 * 1024);
    __shared__ float T[64][65];
    const int t = threadIdx.x;
    const int r0 = blockIdx.y * 64, c0 = blockIdx.x * 64;
#pragma unroll
    for (int e = 0; e < 4; ++e) {
        int row = e * 16 + (t >> 4), c4 = (t & 15) * 4;
        f32x4 v = *(const f32x4*)(W + (r0 + row) * 1024 + c0 + c4);
        T[row][c4] = v[0]; T[row][c4 + 1] = v[1]; T[row][c4 + 2] = v[2]; T[row][c4 + 3] = v[3];
    }
    __syncthreads();
#pragma unroll
    for (int e = 0; e < 4; ++e) {
        int orow = e * 16 + (t >> 4), oc4 = (t & 15) * 4;
        u16x4 pk = { f2b(T[oc4][orow]), f2b(T[oc4 + 1][orow]),
                     f2b(T[oc4 + 2][orow]), f2b(T[oc4 + 3][orow]) };
        *(u16x4*)(Out + (c0 + orow) * 1024 + r0 + oc4) = pk;
    }
}

// ---------------- GEMM: C[8192][1024] = A[8192][1024](bf16) * W (Bt = W^T bf16) -
template <int BIAS>
__global__ __launch_bounds__(256)
void gemm_kernel(const u16* __restrict__ Ab, const u16* __restrict__ Bt,
                 u16* __restrict__ Cb, float* __restrict__ Cf,
                 const float* __restrict__ bias) {
    constexpr int K = 1024;
    __shared__ u16 As[128 * 64];
    __shared__ u16 Bs[128 * 64];
    const int tid = threadIdx.x;
    const int lane = tid & 63, w = tid >> 6;
    const int wr = w >> 1, wc = w & 1;
    const int c = lane & 15, g = lane >> 4;
    const int m0 = blockIdx.y * 128, n0 = blockIdx.x * 128;
    const int sr = lane >> 3, sc = (lane & 7) * 8;   // staging row/col for gload
    f32x4 acc[4][4] = {};
    for (int kt = 0; kt < 16; ++kt) {
        const int k0 = kt * 64;
#pragma unroll
        for (int i = 0; i < 4; ++i) {
            int row = 32 * w + 8 * i;
            gload16(Ab + (size_t)(m0 + row + sr) * K + k0 + sc, &As[row * 64]);
            gload16(Bt + (size_t)(n0 + row + sr) * K + k0 + sc, &Bs[row * 64]);
        }
        __syncthreads();
#pragma unroll
        for (int kk = 0; kk < 2; ++kk) {
            bf16x8 af[4], bfr[4];
#pragma unroll
            for (int m = 0; m < 4; ++m)
                af[m] = *(const bf16x8*)&As[(wr * 64 + m * 16 + c) * 64 + kk * 32 + 8 * g];
#pragma unroll
            for (int n = 0; n < 4; ++n)
                bfr[n] = *(const bf16x8*)&Bs[(wc * 64 + n * 16 + c) * 64 + kk * 32 + 8 * g];
#pragma unroll
            for (int m = 0; m < 4; ++m)
#pragma unroll
                for (int n = 0; n < 4; ++n)
                    acc[m][n] = __builtin_amdgcn_mfma_f32_16x16x32_bf16(af[m], bfr[n], acc[m][n], 0, 0, 0);
        }
        __syncthreads();
    }
#pragma unroll
    for (int n = 0; n < 4; ++n) {
        int col = n0 + wc * 64 + n * 16 + c;
        float bv = BIAS ? bias[col] : 0.0f;
#pragma unroll
        for (int m = 0; m < 4; ++m) {
            int row0 = m0 + wr * 64 + m * 16 + 4 * g;
#pragma unroll
            for (int r = 0; r < 4; ++r) {
                if (BIAS) Cf[(row0 + r) * 1024 + col] = acc[m][n][r] + bv;
                else      Cb[(row0 + r) * 1024 + col] = f2b(acc[m][n][r]);
            }
        }
    }
}

// ---------------- LayerNorm over D=1024 (bf16 in), write bf16 [bh][s][hd] -------
__global__ __launch_bounds__(256)
void ln_kernel(const u16* __restrict__ P, const float* __restrict__ gamma,
               const float* __restrict__ beta, float mul, u16* __restrict__ Out) {
    const int row = blockIdx.x;
    const int tid = threadIdx.x;
    const int lane = tid & 63, w = tid >> 6;
    u16x4 xr = *(const u16x4*)(P + row * 1024 + tid * 4);
    float x0 = bf2f(xr[0]), x1 = bf2f(xr[1]), x2 = bf2f(xr[2]), x3 = bf2f(xr[3]);
    float s = x0 + x1 + x2 + x3;
    float sq = x0 * x0 + x1 * x1 + x2 * x2 + x3 * x3;
#pragma unroll
    for (int m = 1; m < 64; m <<= 1) { s += __shfl_xor(s, m); sq += __shfl_xor(sq, m); }
    __shared__ float red[8];
    if (lane == 0) { red[w] = s; red[4 + w] = sq; }
    __syncthreads();
    float st = red[0] + red[1] + red[2] + red[3];
    float sqt = red[4] + red[5] + red[6] + red[7];
    float mu = st * (1.0f / 1024.0f);
    float var = sqt * (1.0f / 1024.0f) - mu * mu;
    float rs = rsqrtf(var + 1e-5f);
    f32x4 gm = *(const f32x4*)(gamma + tid * 4);
    f32x4 bt = *(const f32x4*)(beta + tid * 4);
    float xs[4] = {x0, x1, x2, x3};
    u16x4 pk;
#pragma unroll
    for (int j = 0; j < 4; ++j)
        pk[j] = f2b(((xs[j] - mu) * rs * gm[j] + bt[j]) * mul);
    const int b = row >> 11, sI = row & 2047;
    const int col = tid * 4, hh = col >> 6, d = col & 63;
    *(u16x4*)(Out + (((b * 16 + hh) * 2048 + sI) << 6) + d) = pk;
}

// ---------------- V transpose: Vt[bh][64][S] (bf16 in/out) ----------------------
__global__ __launch_bounds__(256)
void vt_kernel(const u16* __restrict__ P, u16* __restrict__ Vt) {
    __shared__ u16 T[64][72];
    const int t = threadIdx.x;
    const int bh = blockIdx.y, s0 = blockIdx.x * 64;
    const int b = bh >> 4, h = bh & 15;
#pragma unroll
    for (int e = 0; e < 4; ++e) {
        int row = e * 16 + (t >> 4), c4 = (t & 15) * 4;
        u16x4 v = *(const u16x4*)(P + (b * 2048 + s0 + row) * 1024 + h * 64 + c4);
        *(u16x4*)&T[row][c4] = v;
    }
    __syncthreads();
#pragma unroll
    for (int e = 0; e < 4; ++e) {
        int dd = e * 16 + (t >> 4), s4 = (t & 15) * 4;
        u16x4 pk = { T[s4][dd], T[s4 + 1][dd], T[s4 + 2][dd], T[s4 + 3][dd] };
        *(u16x4*)(Vt + ((size_t)bh * 64 + dd) * 2048 + s0 + s4) = pk;
    }
}

// ---------------- flash attention v5: no-max softmax (shift-invariant) ----------
// 4 waves x 16 q-rows; Ks/Vs double-buffered [64][64] bf16, XOR-swizzled via
// pre-swizzled global_load_lds source. Swapped QK^T -> lane-local exp2 directly
// (|S| <= ~3 for LN'd inputs; softmax is shift-invariant, so no max tracking).
// li accumulates lane-partial, reduced once after the loop.
__global__ __launch_bounds__(256)
void attn_kernel(const u16* __restrict__ Qa, const u16* __restrict__ Ka,
                 const u16* __restrict__ Vt, u16* __restrict__ Xa) {
    __shared__ u16 Ks[2][4096];   // 8KB each: [64][64] swizzled
    __shared__ u16 Vs[2][4096];   // 8KB each: [64][64] swizzled (rows = d)
    __shared__ u16 Pl[4][1024];   // 2KB/wave: [16 q][64 k] swizzled
    const int tid = threadIdx.x;
    const int lane = tid & 63, w = tid >> 6;
    const int c = lane & 15, g = lane >> 4;
    const int bid = blockIdx.x;
    const int bh = (bid & 7) * 8 + ((bid >> 3) & 7);
    const int q0 = (bid >> 6) * 64;
    const int b = bh >> 4, h = bh & 15;

    const int qrow = q0 + w * 16 + c;
    const u16* qptr = Qa + ((size_t)bh * 2048 + qrow) * 64;
    bf16x8 qf0 = *(const bf16x8*)(qptr + 8 * g);
    bf16x8 qf1 = *(const bf16x8*)(qptr + 32 + 8 * g);

    const int sr = lane >> 3;
    const int scg = ((lane & 7) ^ sr) * 8;
    const u16* kA = Ka + ((size_t)bh * 2048 + sr) * 64 + scg;
    const u16* vA = Vt + ((size_t)bh * 64 + sr) * 2048 + scg;
    const int pswz = (c & 7) << 4;

    f32x4 o[4] = {};
    float li = 0.f;
    char* pb = (char*)&Pl[w][0];

    // prologue: stage tile 0 into buf 0
#pragma unroll
    for (int j = 0; j < 2; ++j) {
        const int m = 2 * w + j;
        gload16(kA + (size_t)(8 * m) * 64, &Ks[0][8 * m * 64]);
        gload16(vA + (size_t)(8 * m) * 2048, &Vs[0][8 * m * 64]);
    }
    __syncthreads();

    int cur = 0;
    for (int t = 0; t < 32; ++t) {
        // issue async staging of next tile into the other buffer
        const int tn = (t + 1) & 31;
#pragma unroll
        for (int j = 0; j < 2; ++j) {
            const int m = 2 * w + j;
            gload16(kA + (size_t)(tn * 64 + 8 * m) * 64, &Ks[cur ^ 1][8 * m * 64]);
            gload16(vA + (size_t)(8 * m) * 2048 + tn * 64, &Vs[cur ^ 1][8 * m * 64]);
        }

        // QK^T (swapped): sacc[ct][r] = S[k=16ct+4g+r][q=c]
        const char* kbase = (const char*)&Ks[cur][0];
        f32x4 sacc[4] = {};
        __builtin_amdgcn_s_setprio(1);
#pragma unroll
        for (int ct = 0; ct < 4; ++ct) {
            const int rb = (c + 16 * ct) * 128;
            bf16x8 kf0 = *(const bf16x8*)(kbase + rb + ((16 * g) ^ pswz));
            bf16x8 kf1 = *(const bf16x8*)(kbase + rb + ((64 + 16 * g) ^ pswz));
            sacc[ct] = __builtin_amdgcn_mfma_f32_16x16x32_bf16(kf0, qf0, sacc[ct], 0, 0, 0);
            sacc[ct] = __builtin_amdgcn_mfma_f32_16x16x32_bf16(kf1, qf1, sacc[ct], 0, 0, 0);
        }
        __builtin_amdgcn_s_setprio(0);

        // P = exp2(S) directly (no max shift); lane-partial sum into li
#pragma unroll
        for (int ct = 0; ct < 4; ++ct) {
            float e0 = exp2f(sacc[ct][0]);
            float e1 = exp2f(sacc[ct][1]);
            float e2 = exp2f(sacc[ct][2]);
            float e3 = exp2f(sacc[ct][3]);
            li += (e0 + e1) + (e2 + e3);
            u16x4 pk = { f2b(e0), f2b(e1), f2b(e2), f2b(e3) };
            *(u16x4*)(pb + 128 * c + ((32 * ct + 8 * g) ^ pswz)) = pk;
        }

        // PV from Pl (wave-private) and Vs[cur]
        const char* vb = (const char*)&Vs[cur][0];
        __builtin_amdgcn_s_setprio(1);
#pragma unroll
        for (int s4 = 0; s4 < 2; ++s4) {
            const int co = ((64 * s4 + 16 * g) ^ pswz);
            bf16x8 af = *(const bf16x8*)(pb + 128 * c + co);
#pragma unroll
            for (int n = 0; n < 4; ++n) {
                bf16x8 vf = *(const bf16x8*)(vb + (c + 16 * n) * 128 + co);
                o[n] = __builtin_amdgcn_mfma_f32_16x16x32_bf16(af, vf, o[n], 0, 0, 0);
            }
        }
        __builtin_amdgcn_s_setprio(0);

        __syncthreads();   // next tile staged + all reads of cur done
        cur ^= 1;
    }

    // reduce li across the 4 g-groups once, then normalize
    li += __shfl_xor(li, 16);
    li += __shfl_xor(li, 32);
    float inv = 1.0f / li;
    float i0 = __shfl(inv, 4 * g + 0);
    float i1 = __shfl(inv, 4 * g + 1);
    float i2 = __shfl(inv, 4 * g + 2);
    float i3 = __shfl(inv, 4 * g + 3);
    float iv[4] = {i0, i1, i2, i3};
#pragma unroll
    for (int r = 0; r < 4; ++r) {
        int row = q0 + w * 16 + 4 * g + r;
        u16* xp = Xa + ((size_t)b * 2048 + row) * 1024 + h * 64;
#pragma unroll
        for (int n = 0; n < 4; ++n)
            xp[n * 16 + c] = f2b(o[n][r] * iv[r]);
    }
}

// ---------------- launch --------------------------------------------------------
extern "C" void kernel_launch(void* const* d_in, const int* in_sizes, int n_in,
                              void* d_out, int out_size, void* d_ws, size_t ws_size,
                              hipStream_t stream) {
    const float* q   = (const float*)d_in[0];
    const float* k   = (const float*)d_in[1];
    const float* v   = (const float*)d_in[2];
    const float* Wq  = (const float*)d_in[3];
    const float* Wk  = (const float*)d_in[4];
    const float* Wv  = (const float*)d_in[5];
    const float* Wo  = (const float*)d_in[6];
    const float* bo  = (const float*)d_in[7];
    const float* qg  = (const float*)d_in[8];
    const float* qbt = (const float*)d_in[9];
    const float* kg  = (const float*)d_in[10];
    const float* kbt = (const float*)d_in[11];

    char* ws = (char*)d_ws;
    u16* Wt = (u16*)(ws);                    //  8,388,608 B
    u16* Pb = (u16*)(ws + 8388608);          // 16,777,216 B
    u16* Qa = (u16*)(ws + 25165824);         // 16,777,216 B
    u16* Ka = (u16*)(ws + 41943040);         // 16,777,216 B
    u16* Vt = (u16*)(ws + 58720256);         // 16,777,216 B
    u16* Ib = (u16*)(ws + 75497472);         // 16,777,216 B bf16 input slot (end 92MB)
    u16* Xa = Pb;                            // reuse: P dead after vt_kernel

    const float MUL_Q = 0.04508422002778f;   // (1/32) * log2(e)

    wt_kernel<<<dim3(16, 16, 4), 256, 0, stream>>>(Wq, Wk, Wv, Wo, Wt);

    cvt_kernel<<<4096, 256, 0, stream>>>(q, Ib);
    gemm_kernel<0><<<dim3(8, 64), 256, 0, stream>>>(Ib, Wt, Pb, nullptr, nullptr);
    ln_kernel<<<8192, 256, 0, stream>>>(Pb, qg, qbt, MUL_Q, Qa);

    cvt_kernel<<<4096, 256, 0, stream>>>(k, Ib);
    gemm_kernel<0><<<dim3(8, 64), 256, 0, stream>>>(Ib, Wt + 1048576, Pb, nullptr, nullptr);
    ln_kernel<<<8192, 256, 0, stream>>>(Pb, kg, kbt, 1.0f, Ka);

    cvt_kernel<<<4096, 256, 0, stream>>>(v, Ib);
    gemm_kernel<0><<<dim3(8, 64), 256, 0, stream>>>(Ib, Wt + 2097152, Pb, nullptr, nullptr);
    vt_kernel<<<dim3(32, 64), 256, 0, stream>>>(Pb, Vt);

    attn_kernel<<<2048, 256, 0, stream>>>(Qa, Ka, Vt, Xa);

    gemm_kernel<1><<<dim3(8, 64), 256, 0, stream>>>((const u16*)Xa, Wt + 3145728, nullptr, (float*)d_out, bo);
}